// Round 1
// baseline (679.711 us; speedup 1.0000x reference)
//
#include <hip/hip_runtime.h>
#include <math.h>

// -------- degree --------
__global__ void k_deg(const int* __restrict__ dst, int* __restrict__ deg, int E) {
    int i = blockIdx.x * blockDim.x + threadIdx.x;
    if (i < E) atomicAdd(&deg[dst[i]], 1);
}

__global__ void k_dinv(const int* __restrict__ deg, float* __restrict__ dinv, int n) {
    int i = blockIdx.x * blockDim.x + threadIdx.x;
    if (i < n) dinv[i] = rsqrtf((float)deg[i] + 1.0f);  // +1 self loop; always > 0
}

// -------- layer 1: self-loop init  agg1[i,f] = (x[i]@W1)[f] * dinv[i]^2 --------
__global__ void k_l1_self(const float* __restrict__ x, const float* __restrict__ W1,
                          const float* __restrict__ dinv, float* __restrict__ agg1, int n) {
    long long t = (long long)blockIdx.x * blockDim.x + threadIdx.x;
    if (t >= (long long)n * 128) return;
    int i = (int)(t >> 7), f = (int)(t & 127);
    float h = x[2 * i] * W1[f] + x[2 * i + 1] * W1[128 + f];
    float di = dinv[i];
    agg1[(size_t)i * 128 + f] = h * di * di;
}

// -------- layer 1: edge scatter (recompute x@W1 per edge, K=2 is cheap) --------
__global__ void k_l1_edge(const float* __restrict__ x, const float* __restrict__ W1,
                          const int* __restrict__ src, const int* __restrict__ dst,
                          const float* __restrict__ dinv, float* __restrict__ agg1, int E) {
    long long t = (long long)blockIdx.x * blockDim.x + threadIdx.x;
    if (t >= (long long)E * 128) return;
    int e = (int)(t >> 7), f = (int)(t & 127);
    int s = src[e], d = dst[e];
    float h = x[2 * s] * W1[f] + x[2 * s + 1] * W1[128 + f];
    atomicAdd(&agg1[(size_t)d * 128 + f], h * dinv[s] * dinv[d]);
}

// -------- layer 2: fused  h1 = relu(agg1 + b1); m2 = (h1@W2)*dinv; agg2 init --------
__global__ __launch_bounds__(256) void k_l2_mm(const float* __restrict__ agg1,
                                               const float* __restrict__ b1,
                                               const float* __restrict__ W2,
                                               const float* __restrict__ dinv,
                                               float* __restrict__ m2,
                                               float* __restrict__ agg2, int n) {
    __shared__ float W2s[128 * 64];  // 32 KB
    __shared__ float h1s[4][128];    // 2 KB
    int tid = threadIdx.x;
    int ib = blockIdx.x * 4;
    for (int idx = tid; idx < 128 * 64; idx += 256) W2s[idx] = W2[idx];
    for (int idx = tid; idx < 512; idx += 256) {
        int li = idx >> 7, k = idx & 127;
        int gi = ib + li;
        h1s[li][k] = (gi < n) ? fmaxf(agg1[(size_t)gi * 128 + k] + b1[k], 0.f) : 0.f;
    }
    __syncthreads();
    int li = tid >> 6, f = tid & 63;  // 4 nodes x 64 out-features
    int gi = ib + li;
    if (gi < n) {
        float acc = 0.f;
#pragma unroll
        for (int k = 0; k < 128; ++k) acc = fmaf(h1s[li][k], W2s[k * 64 + f], acc);
        float di = dinv[gi];
        m2[(size_t)gi * 64 + f]   = acc * di;        // pre-scaled by dinv[src]
        agg2[(size_t)gi * 64 + f] = acc * di * di;   // self-loop term
    }
}

// -------- layer 2: edge scatter --------
__global__ void k_l2_edge(const float* __restrict__ m2, const int* __restrict__ src,
                          const int* __restrict__ dst, const float* __restrict__ dinv,
                          float* __restrict__ agg2, int E) {
    long long t = (long long)blockIdx.x * blockDim.x + threadIdx.x;
    if (t >= (long long)E * 64) return;
    int e = (int)(t >> 6), f = (int)(t & 63);
    int s = src[e], d = dst[e];
    atomicAdd(&agg2[(size_t)d * 64 + f], m2[(size_t)s * 64 + f] * dinv[d]);
}

// -------- epilogue: out[i] = sigmoid( relu(agg2[i]+b2) . Wp + bp ) --------
__global__ void k_out(const float* __restrict__ agg2, const float* __restrict__ b2,
                      const float* __restrict__ Wp, const float* __restrict__ bp,
                      float* __restrict__ out, int n) {
    int tid = threadIdx.x;
    int i = blockIdx.x * 4 + (tid >> 6);  // wave per node
    int lane = tid & 63;
    if (i >= n) return;
    float v = fmaxf(agg2[(size_t)i * 64 + lane] + b2[lane], 0.f) * Wp[lane];
    for (int off = 32; off; off >>= 1) v += __shfl_down(v, off);
    if (lane == 0) out[i] = 1.f / (1.f + expf(-(v + bp[0])));
}

extern "C" void kernel_launch(void* const* d_in, const int* in_sizes, int n_in,
                              void* d_out, int out_size, void* d_ws, size_t ws_size,
                              hipStream_t stream) {
    const float* x  = (const float*)d_in[0];
    const int*   ei = (const int*)d_in[1];   // [2, E] int32 (JAX x64 disabled)
    const float* W1 = (const float*)d_in[2];
    const float* b1 = (const float*)d_in[3];
    const float* W2 = (const float*)d_in[4];
    const float* b2 = (const float*)d_in[5];
    const float* Wp = (const float*)d_in[6];
    const float* bp = (const float*)d_in[7];
    float* out = (float*)d_out;

    int n = in_sizes[0] / 2;
    int E = in_sizes[1] / 2;
    const int* src = ei;
    const int* dst = ei + E;

    // workspace carve (all buffers fully initialized every call)
    char* ws = (char*)d_ws;
    size_t off = 0;
    auto alloc = [&](size_t bytes) -> void* {
        void* p = ws + off;
        off += (bytes + 255) & ~(size_t)255;
        return p;
    };
    int*   deg  = (int*)alloc((size_t)n * 4);
    float* dinv = (float*)alloc((size_t)n * 4);
    float* agg1 = (float*)alloc((size_t)n * 128 * 4);
    float* m2   = (float*)alloc((size_t)n * 64 * 4);
    float* agg2 = (float*)alloc((size_t)n * 64 * 4);
    (void)ws_size;

    hipMemsetAsync(deg, 0, (size_t)n * 4, stream);
    k_deg<<<(E + 255) / 256, 256, 0, stream>>>(dst, deg, E);
    k_dinv<<<(n + 255) / 256, 256, 0, stream>>>(deg, dinv, n);
    k_l1_self<<<(int)(((long long)n * 128 + 255) / 256), 256, 0, stream>>>(x, W1, dinv, agg1, n);
    k_l1_edge<<<(int)(((long long)E * 128 + 255) / 256), 256, 0, stream>>>(x, W1, src, dst, dinv, agg1, E);
    k_l2_mm<<<(n + 3) / 4, 256, 0, stream>>>(agg1, b1, W2, dinv, m2, agg2, n);
    k_l2_edge<<<(int)(((long long)E * 64 + 255) / 256), 256, 0, stream>>>(m2, src, dst, dinv, agg2, E);
    k_out<<<(n + 3) / 4, 256, 0, stream>>>(agg2, b2, Wp, bp, out, n);
}